// Round 11
// baseline (359.375 us; speedup 1.0000x reference)
//
#include <hip/hip_runtime.h>
#include <math.h>

#define B_ 16
#define N_ 512
#define D_ 32
#define E_ 8176
#define SLEFT_ 16384
#define FSS_ 601
#define BN_ (B_*N_)            // 8192
#define BE_ (B_*E_)            // 130816
#define NSROW_ (SLEFT_ + 2*E_) // 32736
#define OUT_R_ (B_*FSS_)       // 9616
#define HLD_ 768               // combined width: reward 0..639, next 640..767
#define CAP_ 128               // per-node source bin capacity
#define KXB_ 736               // xb-space width: 0..607 reward, 608..735 next

typedef __attribute__((ext_vector_type(8))) short short8;
typedef __attribute__((ext_vector_type(4))) float f32x4;

typedef __attribute__((address_space(3))) uint lds_uint;
typedef __attribute__((address_space(1))) const uint g_uint;

__device__ __forceinline__ void gl_lds16(const ushort* gp, ushort* lp) {
  __builtin_amdgcn_global_load_lds((g_uint*)gp, (lds_uint*)lp, 16, 0, 0);
}

__device__ __forceinline__ ushort f2b(float f) {
  uint u = __builtin_bit_cast(uint, f);
  u += 0x7FFFu + ((u >> 16) & 1u);
  return (ushort)(u >> 16);
}
__device__ __forceinline__ float b2f(ushort h) {
  return __builtin_bit_cast(float, ((uint)h) << 16);
}

// ------- fused setup: edge-binning | sa | ns-tail copy | weight transpose --

struct SetupP {
  const float* ns; const int* a;
  int* cnt; int* bins; ushort* sa; float* outp;
  const float* Wr[4]; const float* Wn[4]; ushort* T[4];
};

__global__ __launch_bounds__(256) void k_setup(SetupP p) {
  __shared__ float tile[32][33];
  int blk = blockIdx.x;
  if (blk < 511) {
    int idx = blk*256 + threadIdx.x;
    if (idx >= BE_) return;
    int b = idx / E_;
    int j = idx - b*E_;
    const float* row = p.ns + (size_t)b*NSROW_;
    int s = (int)row[SLEFT_ + j];
    int r = (int)row[SLEFT_ + E_ + j];
    int dst = b*N_ + r;
    int pos = atomicAdd(&p.cnt[dst], 1);
    if (pos < CAP_) p.bins[(size_t)dst*CAP_ + pos] = b*N_ + s;
    return;
  }
  if (blk < 767) {
    // sa build, vectorized: 8 cols per thread
    int it = (blk-511)*256 + threadIdx.x;    // [0, 65536)
    int v = it >> 3, c0 = (it & 7) * 8;
    int b = v >> 9, n = v & 511;
    short8 ov;
    if (c0 < 32) {
      const float* src = p.ns + (size_t)b*NSROW_ + n*32 + c0;
      #pragma unroll
      for (int j=0;j<8;j++) ov[j] = (short)f2b(src[j]);
    } else {
      #pragma unroll
      for (int j=0;j<8;j++) ov[j] = 0;
      if (c0 == 32) ov[0] = (short)f2b((p.a[b]==n) ? 1.f : 0.f);
    }
    *(short8*)&p.sa[(size_t)v*64 + c0] = ov;
    return;
  }
  if (blk < 1023) {
    // ns tail passthrough: out[OUT_R + b*NSROW + j] = ns[b][j], j in [SLEFT,NSROW)
    int it = (blk-767)*256 + threadIdx.x;    // [0, 65536)
    int b = it >> 12;                        // 4096 float4-slots per graph
    int r = it & 4095;
    if (r < (NSROW_ - SLEFT_)/4) {           // 4088
      const float4* src = (const float4*)(p.ns + (size_t)b*NSROW_ + SLEFT_) + r;
      float4* dst = (float4*)(p.outp + (size_t)OUT_R_ + (size_t)b*NSROW_ + SLEFT_) + r;
      *dst = *src;
    }
    return;
  }
  int t = blk - 1023;
  int s, base, KP, DINR, DINN, DOUTN, KOFF;
  if (t < 48)        { s=0; base=0;    KP=64;  DINR=33;  DINN=33;  DOUTN=128; KOFF=0;   }
  else if (t < 600)  { s=1; base=48;   KP=736; DINR=601; DINN=128; DOUTN=64;  KOFF=608; }
  else if (t < 1104) { s=2; base=600;  KP=672; DINR=601; DINN=64;  DOUTN=64;  KOFF=608; }
  else               { s=3; base=1104; KP=672; DINR=601; DINN=64;  DOUTN=32;  KOFF=608; }
  int ti = t - base;
  int kt = ti / 24, nt = ti - kt*24;
  int k0 = kt*32, n0 = nt*32;
  if (k0 >= KP) return;            // guard: section over-launch must not OOB
  int tid = threadIdx.x;
  int cc = tid & 31, rr = tid >> 5;
  #pragma unroll
  for (int it=0; it<4; it++) {
    int k = k0 + it*8 + rr;
    int n = n0 + cc;
    float v = 0.f;
    if (n < 640) { if (n < 601 && k < DINR) v = p.Wr[s][(size_t)k*601 + n]; }
    else { int nn = n-640, kk = k-KOFF;
           if (nn < DOUTN && kk >= 0 && kk < DINN) v = p.Wn[s][(size_t)kk*DOUTN + nn]; }
    tile[it*8+rr][cc] = v;
  }
  __syncthreads();
  #pragma unroll
  for (int it=0; it<4; it++) {
    int n = n0 + it*8 + rr;
    int k = k0 + cc;
    p.T[s][(size_t)n*KP + k] = f2b(tile[cc][it*8+rr]);
  }
}

// ---------------- MFMA bf16 GEMM, 32x128 tile + atomic final es/ed --------
// Occupancy experiment: M-tile 64->32 doubles the grid to 1536 blocks
// (6 blocks/CU, 24 waves/CU vs 12) so cross-block wave overlap can hide the
// per-K-step vmcnt drain (m114 mechanism; grid was the binding occupancy
// limit at 768 blocks). Per wave: 32 rows x 32 cols, acc 2x2, 4 MFMA/step.
// Affine 1-D grid: bid&7 == graph&7 (matches agg/lnfin XCD pinning).

__global__ __launch_bounds__(256) void k_gemm(const ushort* __restrict__ A,
                                              const ushort* __restrict__ Bt,
                                              ushort* __restrict__ C,
                                              float* __restrict__ esed, // es_r|ed_r|es_n|ed_n
                                              const float* __restrict__ asr,
                                              const float* __restrict__ adr,
                                              const float* __restrict__ asn,
                                              const float* __restrict__ adn,
                                              int Astr, int Kpad, int dn,
                                              int kRewEnd, int kNextBeg) {
  __shared__ ushort Asm[32*32];
  __shared__ ushort Bsm[128*32];
  int tid = threadIdx.x;
  int bid = blockIdx.x;                 // 0..1535
  int x = bid & 7, q = bid >> 3;        // q in [0,192)
  int rbl = q & 31, cb = q >> 5;        // rbl 0..31, cb 0..5
  int grp = x + ((rbl >> 4) << 3);      // graph 0..15, grp&7 == bid&7
  int rowBase = grp*512 + (rbl & 15) * 32;
  int colBase = cb * 128;
  int kBeg = (cb == 5) ? kNextBeg : 0;
  int kEnd = (cb == 5) ? Kpad : kRewEnd;
  int wave = tid >> 6, lane = tid & 63;
  int wc = wave * 32;
  int lm = lane & 15, lk = (lane >> 4) * 8;

  f32x4 acc[2][2];
  #pragma unroll
  for (int i=0;i<2;i++)
    #pragma unroll
    for (int j=0;j<2;j++) acc[i][j] = (f32x4){0.f,0.f,0.f,0.f};

  int t0 = tid, t1 = tid + 256;
  int ar = t0 >> 2, ac8 = (t0 & 3) * 8;    // A: threads 0..127 stage 32x32
  const ushort* Bg0 = Bt + (size_t)(colBase + (t0>>2))*Kpad + (t0&3)*8;
  const ushort* Bg1 = Bt + (size_t)(colBase + (t1>>2))*Kpad + (t1&3)*8;
  ushort* Bl0 = &Bsm[t0*8];
  ushort* Bl1 = &Bsm[t1*8];
  ushort* Al0 = &Asm[t0*8];

  const ushort* Ag = A + (size_t)(rowBase + ar)*Astr + ac8;

  for (int k0 = kBeg; k0 < kEnd; k0 += 32) {
    gl_lds16(Bg0 + k0, Bl0);
    gl_lds16(Bg1 + k0, Bl1);
    if (tid < 128) gl_lds16(Ag + k0, Al0);   // wave-uniform branch (waves 0,1)
    __syncthreads();
    short8 af[2], bfr[2];
    #pragma unroll
    for (int i=0;i<2;i++) af[i]  = *(short8*)&Asm[(i*16 + lm)*32 + lk];
    #pragma unroll
    for (int j=0;j<2;j++) bfr[j] = *(short8*)&Bsm[(wc + j*16 + lm)*32 + lk];
    #pragma unroll
    for (int i=0;i<2;i++)
      #pragma unroll
      for (int j=0;j<2;j++)
        acc[i][j] = __builtin_amdgcn_mfma_f32_16x16x32_bf16(af[i], bfr[j], acc[i][j], 0,0,0);
    __syncthreads();
  }

  float asv[2], adv[2];
  #pragma unroll
  for (int j=0;j<2;j++) {
    int col = colBase + wc + j*16 + lm;
    float s = 0.f, d = 0.f;
    if (col < 601)      { s = asr[col];     d = adr[col]; }
    else if (col >= 640 && col - 640 < dn) { s = asn[col-640]; d = adn[col-640]; }
    asv[j] = s; adv[j] = d;
  }
  int cr = lane >> 4;
  float* esp = (cb < 5) ? esed : esed + 2*BN_;
  #pragma unroll
  for (int i=0;i<2;i++) {
    #pragma unroll
    for (int j=0;j<2;j++) {
      int col = colBase + wc + j*16 + lm;
      #pragma unroll
      for (int g=0; g<4; g++) {
        int row = rowBase + i*16 + cr*4 + g;
        C[(size_t)row*HLD_ + col] = f2b(acc[i][j][g]);
      }
    }
    #pragma unroll
    for (int g=0; g<4; g++) {
      float se = 0.f, sd = 0.f;
      #pragma unroll
      for (int j=0;j<2;j++) { se += acc[i][j][g]*asv[j]; sd += acc[i][j][g]*adv[j]; }
      #pragma unroll
      for (int o=1;o<16;o<<=1) { se += __shfl_xor(se,o,64); sd += __shfl_xor(sd,o,64); }
      if (lm == 0) {
        int row = rowBase + i*16 + cr*4 + g;
        atomicAdd(&esp[row], se);
        atomicAdd(&esp[BN_ + row], sd);
      }
    }
  }
}

// ---------------- combined softmax + aggregation (one wave per node) ------
// L<3: writes gbuf (bf16). L==3 (doRsum): skips gbuf entirely; reward cols
// LDS-reduced over the block's 4 nodes and atomicAdd'ed into out[0..OUT_R),
// next-head cols written as f32 to out's ns_new section (same bf16-rounded
// values the old k_final produced).

__global__ __launch_bounds__(256) void k_agg(const ushort* __restrict__ h,
                                             const float* __restrict__ esed,
                                             const int* __restrict__ cnt,
                                             const int* __restrict__ bins,
                                             const float* __restrict__ bias_r,
                                             const float* __restrict__ bias_n,
                                             ushort* __restrict__ g,
                                             float* __restrict__ outp,
                                             int dn, int doRsum) {
  __shared__ float RW[4][608];
  const float* es_r = esed;
  const float* ed_r = esed + BN_;
  const float* es_n = esed + 2*BN_;
  const float* ed_n = esed + 3*BN_;
  int wid = threadIdx.x>>6, lane = threadIdx.x&63;
  int bid = blockIdx.x;
  int xcd = bid & 7, slot = bid >> 3;
  int graph = xcd + ((slot >> 7) << 3);
  int nloc = (slot & 127)*4 + wid;          // node within graph
  int v = graph*512 + nloc;
  int s0 = v * CAP_;
  int deg = cnt[v]; if (deg > CAP_) deg = CAP_;
  float edr = ed_r[v], edn = ed_n[v];

  int nch = (640 + dn + 7) >> 3;   // 96 / 88 / 84 real 8-col chunks
  int ch0 = lane, ch1 = lane + 64;
  bool a1 = ch1 < nch;
  bool c1r = ch1 < 80;
  float acc0[8], acc1[8];
  #pragma unroll
  for (int q=0;q<8;q++){ acc0[q]=0.f; acc1[q]=0.f; }

  if (deg <= 64) {
    bool has = lane < deg;
    int u = 0; float er = -__builtin_inff(), en = -__builtin_inff();
    if (has) {
      u = bins[s0 + lane];
      er = es_r[u] + edr; er = er > 0.f ? er : 0.2f*er;
      en = es_n[u] + edn; en = en > 0.f ? en : 0.2f*en;
    }
    float mr = er, mn = en;
    #pragma unroll
    for (int o=32;o;o>>=1) { mr = fmaxf(mr, __shfl_xor(mr,o,64)); mn = fmaxf(mn, __shfl_xor(mn,o,64)); }
    float pr = has ? __expf(er - mr) : 0.f;
    float pn = has ? __expf(en - mn) : 0.f;
    float dr = pr, dnm = pn;
    #pragma unroll
    for (int o=32;o;o>>=1) { dr += __shfl_xor(dr,o,64); dnm += __shfl_xor(dnm,o,64); }
    pr *= 1.f/(dr + 1e-16f);
    pn *= 1.f/(dnm + 1e-16f);

    for (int t0 = 0; t0 < deg; t0 += 4) {
      int nt = deg - t0; if (nt > 4) nt = 4;
      short8 va[4], vb[4];
      float w0[4], w1[4];
      #pragma unroll
      for (int q=0;q<4;q++) {
        if (q < nt) {
          int uu = __shfl(u, t0+q, 64);
          w0[q] = __shfl(pr, t0+q, 64);
          w1[q] = __shfl(pn, t0+q, 64);
          const ushort* hp = h + (size_t)uu*HLD_;
          va[q] = *(const short8*)&hp[ch0*8];
          vb[q] = a1 ? *(const short8*)&hp[ch1*8] : short8{};
        } else {
          w0[q] = 0.f; w1[q] = 0.f; va[q] = short8{}; vb[q] = short8{};
        }
      }
      #pragma unroll
      for (int q=0;q<4;q++) {
        #pragma unroll
        for (int r=0;r<8;r++) acc0[r] += w0[q] * b2f((ushort)va[q][r]);
        if (a1) {
          float wv = c1r ? w0[q] : w1[q];
          #pragma unroll
          for (int r=0;r<8;r++) acc1[r] += wv * b2f((ushort)vb[q][r]);
        }
      }
    }
  } else {
    int e0 = s0 + deg;
    float mr = -__builtin_inff(), mn = -__builtin_inff();
    for (int j = s0 + lane; j < e0; j += 64) {
      int u = bins[j];
      float er = es_r[u] + edr; er = er>0.f?er:0.2f*er;
      float en = es_n[u] + edn; en = en>0.f?en:0.2f*en;
      mr = fmaxf(mr, er); mn = fmaxf(mn, en);
    }
    #pragma unroll
    for (int o=32;o;o>>=1) { mr=fmaxf(mr,__shfl_xor(mr,o,64)); mn=fmaxf(mn,__shfl_xor(mn,o,64)); }
    float dr=0.f, dnm=0.f;
    for (int j = s0 + lane; j < e0; j += 64) {
      int u = bins[j];
      float er = es_r[u] + edr; er = er>0.f?er:0.2f*er;
      float en = es_n[u] + edn; en = en>0.f?en:0.2f*en;
      dr += __expf(er-mr); dnm += __expf(en-mn);
    }
    #pragma unroll
    for (int o=32;o;o>>=1) { dr+=__shfl_xor(dr,o,64); dnm+=__shfl_xor(dnm,o,64); }
    float ir = 1.f/(dr+1e-16f), in_ = 1.f/(dnm+1e-16f);
    for (int j = s0; j < e0; ++j) {
      int uu = bins[j];
      float er = es_r[uu] + edr; er = er>0.f?er:0.2f*er;
      float en = es_n[uu] + edn; en = en>0.f?en:0.2f*en;
      float wr2 = __expf(er-mr)*ir, wn2 = __expf(en-mn)*in_;
      const ushort* hp = h + (size_t)uu*HLD_;
      short8 hv = *(const short8*)&hp[ch0*8];
      #pragma unroll
      for (int q=0;q<8;q++) acc0[q] += wr2 * b2f((ushort)hv[q]);
      if (a1) {
        short8 hv2 = *(const short8*)&hp[ch1*8];
        float wv = c1r ? wr2 : wn2;
        #pragma unroll
        for (int q=0;q<8;q++) acc1[q] += wv * b2f((ushort)hv2[q]);
      }
    }
  }

  ushort* gv = g + (size_t)v*HLD_;
  {
    int cb = ch0*8;
    short8 ov;
    #pragma unroll
    for (int q=0;q<8;q++) ov[q] = (short)f2b(acc0[q] + bias_r[cb+q]);
    if (!doRsum) {
      *(short8*)&gv[cb] = ov;
    } else {
      #pragma unroll
      for (int q=0;q<8;q++) RW[wid][cb+q] = b2f((ushort)ov[q]);
    }
  }
  if (a1) {
    int cb = ch1*8;
    short8 ov;
    #pragma unroll
    for (int q=0;q<8;q++) {
      int c = cb+q;
      float val;
      if (c < 601)                         val = acc1[q] + bias_r[c];
      else if (c >= 640 && (c-640) < dn)   val = acc1[q] + bias_n[c-640];
      else                                 val = 0.f;
      ov[q] = (short)f2b(val);
    }
    if (!doRsum) {
      *(short8*)&gv[cb] = ov;
    } else {
      if (cb < 608) {
        #pragma unroll
        for (int q=0;q<8;q++) {
          int c = cb+q;
          RW[wid][c] = (c < 601) ? b2f((ushort)ov[q]) : 0.f;
        }
      }
      // next-head f32 write straight to out's ns_new section
      #pragma unroll
      for (int q=0;q<8;q++) {
        int c = cb+q;
        if (c >= 640 && (c-640) < dn) {
          outp[(size_t)OUT_R_ + (size_t)graph*NSROW_ + nloc*D_ + (c-640)] =
              b2f((ushort)ov[q]);
        }
      }
    }
  }
  if (doRsum) {
    if (!a1 && ch1*8 < 608) {     // safety for small nch
      #pragma unroll
      for (int q=0;q<8;q++) RW[wid][ch1*8+q] = 0.f;
    }
    __syncthreads();
    for (int c = threadIdx.x; c < 601; c += 256) {
      float s = RW[0][c] + RW[1][c] + RW[2][c] + RW[3][c];
      atomicAdd(&outp[(size_t)graph*FSS_ + c], s);
    }
  }
}

// ---------------- fused LN: stats + finalize + materialize xbuf -----------
// 1-D grid 192, bid&7 == graph&7 (XCD-affine with agg/gemm).

__global__ __launch_bounds__(256) void k_lnfin(const ushort* __restrict__ g,
                                               const float* __restrict__ scr,
                                               const float* __restrict__ ofr,
                                               const float* __restrict__ scn,
                                               const float* __restrict__ ofn,
                                               ushort* __restrict__ xbuf,
                                               int dn) {
  int bid = blockIdx.x;            // 0..191
  int x = bid & 7, sl = bid >> 3;  // sl in [0,24)
  int b = x + ((sl >= 12) ? 8 : 0);
  int cbk = (sl >= 12) ? (sl - 12) : sl;   // col-block 0..11
  int t = threadIdx.x;
  int c8l = t & 7;               // 8 col-chunks of 8 cols -> 64 cols/block
  int rg  = t >> 3;              // 32 row-groups of 16 rows
  int xb8 = cbk*64 + c8l*8;
  bool okc = xb8 < KXB_;
  int gcol8 = (xb8 < 608) ? xb8 : xb8 + 32;
  float s8[8], q8[8];
  #pragma unroll
  for (int j=0;j<8;j++){ s8[j]=0.f; q8[j]=0.f; }
  if (okc) {
    const ushort* gp = g + (size_t)(b*N_ + rg*16)*HLD_ + gcol8;
    #pragma unroll
    for (int i=0;i<16;i++) {
      short8 v = *(const short8*)&gp[(size_t)i*HLD_];
      #pragma unroll
      for (int j=0;j<8;j++) {
        float xv = b2f((ushort)v[j]);
        s8[j] += xv; q8[j] += xv*xv;
      }
    }
  }
  __shared__ float S[32][64], Q[32][64];
  __shared__ float MU[64], AD[64];
  #pragma unroll
  for (int j=0;j<8;j++){ S[rg][c8l*8+j]=s8[j]; Q[rg][c8l*8+j]=q8[j]; }
  __syncthreads();
  if (t < 64) {
    int xb = cbk*64 + t;
    float mul = 0.f, add = 0.f;
    if (xb < KXB_) {
      float ts=0.f, tq=0.f;
      #pragma unroll
      for (int r=0;r<32;r++){ ts += S[r][t]; tq += Q[r][t]; }
      bool valid; float scale, offs;
      if (xb < 608) { valid = xb < 601;
                      scale = valid ? scr[xb] : 0.f; offs = valid ? ofr[xb] : 0.f; }
      else { int cn = xb - 608; valid = cn < dn;
             scale = valid ? scn[cn] : 0.f; offs = valid ? ofn[cn] : 0.f; }
      if (valid) {
        float mu = ts*(1.f/N_);
        float var = tq*(1.f/N_) - mu*mu;
        float rs = rsqrtf(var+1e-5f);
        mul = rs*scale;
        add = offs - mu*rs*scale;
      }
    }
    MU[t] = mul; AD[t] = add;
  }
  __syncthreads();
  if (okc) {
    float mu8[8], ad8[8];
    #pragma unroll
    for (int j=0;j<8;j++){ mu8[j]=MU[c8l*8+j]; ad8[j]=AD[c8l*8+j]; }
    const ushort* gp = g + (size_t)(b*N_ + rg*16)*HLD_ + gcol8;
    ushort* xp = xbuf + (size_t)(b*N_ + rg*16)*KXB_ + xb8;
    #pragma unroll
    for (int i=0;i<16;i++) {
      short8 v = *(const short8*)&gp[(size_t)i*HLD_];
      short8 ov;
      #pragma unroll
      for (int j=0;j<8;j++) {
        float y = b2f((ushort)v[j]) * mu8[j] + ad8[j];
        y = y > 0.f ? y : 0.f;
        ov[j] = (short)f2b(y);
      }
      *(short8*)&xp[(size_t)i*KXB_] = ov;
    }
  }
}

// ---------------- host driver ----------------

extern "C" void kernel_launch(void* const* d_in, const int* in_sizes, int n_in,
                              void* d_out, int out_size, void* d_ws, size_t ws_size,
                              hipStream_t stream) {
  const float* ns = (const float*)d_in[0];
  const int*   a  = (const int*)d_in[1];

  const float *W[4], *As[4], *Ad[4], *Bb[4], *Sc[3], *Of[3];
  const float *rW[4], *rAs[4], *rAd[4], *rBb[4], *rSc[3], *rOf[3];
  int p = 2;
  for (int i=0;i<4;i++){
    W[i]=(const float*)d_in[p++]; As[i]=(const float*)d_in[p++];
    Ad[i]=(const float*)d_in[p++]; Bb[i]=(const float*)d_in[p++];
    if (i<3){ Sc[i]=(const float*)d_in[p++]; Of[i]=(const float*)d_in[p++]; }
  }
  for (int i=0;i<4;i++){
    rW[i]=(const float*)d_in[p++]; rAs[i]=(const float*)d_in[p++];
    rAd[i]=(const float*)d_in[p++]; rBb[i]=(const float*)d_in[p++];
    if (i<3){ rSc[i]=(const float*)d_in[p++]; rOf[i]=(const float*)d_in[p++]; }
  }

  char* w = (char*)d_ws;
  auto carve = [&](size_t bytes)->void* {
    void* r = (void*)w;
    w += (bytes + 255) & ~(size_t)255;
    return r;
  };
  ushort* hbuf = (ushort*)carve((size_t)BN_*HLD_*2);
  ushort* gbuf = (ushort*)carve((size_t)BN_*HLD_*2);
  ushort* xbuf = (ushort*)carve((size_t)BN_*KXB_*2);   // LN'd activations
  ushort* sabf = (ushort*)carve((size_t)BN_*64*2);
  // zero-region: cnt | esed[4 layers] — one memset covers all
  int* cnt     = (int*)carve((size_t)(BN_ + 16*BN_)*4);
  float* esedL = (float*)(cnt + BN_);                // 4 x [4*BN]
  int* bins    = (int*)carve((size_t)BN_*CAP_*4);    // 4 MB
  ushort* Wt[4];
  Wt[0] = (ushort*)carve((size_t)768*64*2);
  Wt[1] = (ushort*)carve((size_t)768*736*2);
  Wt[2] = (ushort*)carve((size_t)768*672*2);
  Wt[3] = (ushort*)carve((size_t)768*672*2);

  float* out = (float*)d_out;

  hipMemsetAsync(cnt, 0, (size_t)(BN_ + 16*BN_)*4, stream);
  hipMemsetAsync(out, 0, (size_t)OUT_R_*4, stream);   // reward accum target

  SetupP sp;
  sp.ns = ns; sp.a = a; sp.cnt = cnt; sp.bins = bins; sp.sa = sabf; sp.outp = out;
  for (int i=0;i<4;i++){ sp.Wr[i]=rW[i]; sp.Wn[i]=W[i]; sp.T[i]=Wt[i]; }
  // sections: 511 (edges) + 256 (sa) + 256 (ns tail) + 1608 (transpose)
  k_setup<<<2631, 256, 0, stream>>>(sp);

  int Kp[4]   = { 64, 736, 672, 672 };
  int dns[4]  = { 128, 64, 64, 32 };
  int kRe[4]  = { 64, 608, 608, 608 };
  int kNb[4]  = { 0, 608, 608, 608 };

  for (int L=0; L<4; ++L) {
    float* esed = esedL + (size_t)L*4*BN_;
    const ushort* Ain = (L==0) ? sabf : xbuf;
    int Astr        = (L==0) ? 64 : KXB_;
    k_gemm<<<1536, 256, 0, stream>>>(Ain, Wt[L], hbuf, esed,
                                     rAs[L], rAd[L], As[L], Ad[L],
                                     Astr, Kp[L], dns[L], kRe[L], kNb[L]);
    k_agg<<<BN_/4, 256, 0, stream>>>(hbuf, esed, cnt, bins,
                                     rBb[L], Bb[L], gbuf, out,
                                     dns[L], (L==3)?1:0);
    if (L < 3) {
      k_lnfin<<<192, 256, 0, stream>>>(gbuf, rSc[L], rOf[L], Sc[L], Of[L],
                                       xbuf, dns[L]);
    }
  }
}

// Round 12
// 333.384 us; speedup vs baseline: 1.0780x; 1.0780x over previous
//
#include <hip/hip_runtime.h>
#include <math.h>

#define B_ 16
#define N_ 512
#define D_ 32
#define E_ 8176
#define SLEFT_ 16384
#define FSS_ 601
#define BN_ (B_*N_)            // 8192
#define BE_ (B_*E_)            // 130816
#define NSROW_ (SLEFT_ + 2*E_) // 32736
#define OUT_R_ (B_*FSS_)       // 9616
#define HLD_ 768               // combined width: reward 0..639, next 640..767
#define CAP_ 128               // per-node source bin capacity
#define KXB_ 736               // xb-space width: 0..607 reward, 608..735 next

typedef __attribute__((ext_vector_type(8))) short short8;
typedef __attribute__((ext_vector_type(4))) float f32x4;

typedef __attribute__((address_space(3))) uint lds_uint;
typedef __attribute__((address_space(1))) const uint g_uint;

__device__ __forceinline__ void gl_lds16(const ushort* gp, ushort* lp) {
  __builtin_amdgcn_global_load_lds((g_uint*)gp, (lds_uint*)lp, 16, 0, 0);
}

__device__ __forceinline__ ushort f2b(float f) {
  uint u = __builtin_bit_cast(uint, f);
  u += 0x7FFFu + ((u >> 16) & 1u);
  return (ushort)(u >> 16);
}
__device__ __forceinline__ float b2f(ushort h) {
  return __builtin_bit_cast(float, ((uint)h) << 16);
}

// ------- fused setup: edge-binning | sa | ns-tail copy | weight transpose --

struct SetupP {
  const float* ns; const int* a;
  int* cnt; int* bins; ushort* sa; float* outp;
  const float* Wr[4]; const float* Wn[4]; ushort* T[4];
};

__global__ __launch_bounds__(256) void k_setup(SetupP p) {
  __shared__ float tile[32][33];
  int blk = blockIdx.x;
  if (blk < 511) {
    int idx = blk*256 + threadIdx.x;
    if (idx >= BE_) return;
    int b = idx / E_;
    int j = idx - b*E_;
    const float* row = p.ns + (size_t)b*NSROW_;
    int s = (int)row[SLEFT_ + j];
    int r = (int)row[SLEFT_ + E_ + j];
    int dst = b*N_ + r;
    int pos = atomicAdd(&p.cnt[dst], 1);
    if (pos < CAP_) p.bins[(size_t)dst*CAP_ + pos] = b*N_ + s;
    return;
  }
  if (blk < 767) {
    // sa build, vectorized: 8 cols per thread
    int it = (blk-511)*256 + threadIdx.x;    // [0, 65536)
    int v = it >> 3, c0 = (it & 7) * 8;
    int b = v >> 9, n = v & 511;
    short8 ov;
    if (c0 < 32) {
      const float* src = p.ns + (size_t)b*NSROW_ + n*32 + c0;
      #pragma unroll
      for (int j=0;j<8;j++) ov[j] = (short)f2b(src[j]);
    } else {
      #pragma unroll
      for (int j=0;j<8;j++) ov[j] = 0;
      if (c0 == 32) ov[0] = (short)f2b((p.a[b]==n) ? 1.f : 0.f);
    }
    *(short8*)&p.sa[(size_t)v*64 + c0] = ov;
    return;
  }
  if (blk < 1023) {
    // ns tail passthrough: out[OUT_R + b*NSROW + j] = ns[b][j], j in [SLEFT,NSROW)
    int it = (blk-767)*256 + threadIdx.x;    // [0, 65536)
    int b = it >> 12;                        // 4096 float4-slots per graph
    int r = it & 4095;
    if (r < (NSROW_ - SLEFT_)/4) {           // 4088
      const float4* src = (const float4*)(p.ns + (size_t)b*NSROW_ + SLEFT_) + r;
      float4* dst = (float4*)(p.outp + (size_t)OUT_R_ + (size_t)b*NSROW_ + SLEFT_) + r;
      *dst = *src;
    }
    return;
  }
  int t = blk - 1023;
  int s, base, KP, DINR, DINN, DOUTN, KOFF;
  if (t < 48)        { s=0; base=0;    KP=64;  DINR=33;  DINN=33;  DOUTN=128; KOFF=0;   }
  else if (t < 600)  { s=1; base=48;   KP=736; DINR=601; DINN=128; DOUTN=64;  KOFF=608; }
  else if (t < 1104) { s=2; base=600;  KP=672; DINR=601; DINN=64;  DOUTN=64;  KOFF=608; }
  else               { s=3; base=1104; KP=672; DINR=601; DINN=64;  DOUTN=32;  KOFF=608; }
  int ti = t - base;
  int kt = ti / 24, nt = ti - kt*24;
  int k0 = kt*32, n0 = nt*32;
  if (k0 >= KP) return;            // guard: section over-launch must not OOB
  int tid = threadIdx.x;
  int cc = tid & 31, rr = tid >> 5;
  #pragma unroll
  for (int it=0; it<4; it++) {
    int k = k0 + it*8 + rr;
    int n = n0 + cc;
    float v = 0.f;
    if (n < 640) { if (n < 601 && k < DINR) v = p.Wr[s][(size_t)k*601 + n]; }
    else { int nn = n-640, kk = k-KOFF;
           if (nn < DOUTN && kk >= 0 && kk < DINN) v = p.Wn[s][(size_t)kk*DOUTN + nn]; }
    tile[it*8+rr][cc] = v;
  }
  __syncthreads();
  #pragma unroll
  for (int it=0; it<4; it++) {
    int n = n0 + it*8 + rr;
    int k = k0 + cc;
    p.T[s][(size_t)n*KP + k] = f2b(tile[cc][it*8+rr]);
  }
}

// ---------------- MFMA bf16 GEMM, 64x128 tile + atomic final es/ed --------
// Verified champion body (R9/R10): 1-D affine grid (bid&7 == graph&7),
// 32-K single-buffered loop, pure global_load_lds staging. Structural
// variants measured and rejected: source dbuf (+16us), BK=64 (+6us),
// 32x128/2x blocks (+25us) — this shape balances staging bytes vs MFMA
// per barrier best.

__global__ __launch_bounds__(256) void k_gemm(const ushort* __restrict__ A,
                                              const ushort* __restrict__ Bt,
                                              ushort* __restrict__ C,
                                              float* __restrict__ esed, // es_r|ed_r|es_n|ed_n
                                              const float* __restrict__ asr,
                                              const float* __restrict__ adr,
                                              const float* __restrict__ asn,
                                              const float* __restrict__ adn,
                                              int Astr, int Kpad, int dn,
                                              int kRewEnd, int kNextBeg) {
  __shared__ ushort Asm[64*32];
  __shared__ ushort Bsm[128*32];
  int tid = threadIdx.x;
  int bid = blockIdx.x;                 // 0..767
  int x = bid & 7, q = bid >> 3;        // q in [0,96)
  int rbl = q & 15, cb = q >> 4;        // rbl 0..15, cb 0..5
  int grp = x + ((rbl >> 3) << 3);      // graph 0..15, grp&7 == bid&7
  int rowBase = (grp*8 + (rbl & 7)) * 64;
  int colBase = cb * 128;
  int kBeg = (cb == 5) ? kNextBeg : 0;
  int kEnd = (cb == 5) ? Kpad : kRewEnd;
  int wave = tid >> 6, lane = tid & 63;
  int wr = (wave >> 1) * 32, wc = (wave & 1) * 64;
  int lm = lane & 15, lk = (lane >> 4) * 8;

  f32x4 acc[2][4];
  #pragma unroll
  for (int i=0;i<2;i++)
    #pragma unroll
    for (int j=0;j<4;j++) acc[i][j] = (f32x4){0.f,0.f,0.f,0.f};

  int t0 = tid, t1 = tid + 256;
  int ar = t0 >> 2, ac8 = (t0 & 3) * 8;
  const ushort* Bg0 = Bt + (size_t)(colBase + (t0>>2))*Kpad + (t0&3)*8;
  const ushort* Bg1 = Bt + (size_t)(colBase + (t1>>2))*Kpad + (t1&3)*8;
  ushort* Bl0 = &Bsm[t0*8];
  ushort* Bl1 = &Bsm[t1*8];
  ushort* Al0 = &Asm[t0*8];

  const ushort* Ag = A + (size_t)(rowBase + ar)*Astr + ac8;

  for (int k0 = kBeg; k0 < kEnd; k0 += 32) {
    gl_lds16(Bg0 + k0, Bl0);
    gl_lds16(Bg1 + k0, Bl1);
    gl_lds16(Ag + k0, Al0);
    __syncthreads();
    short8 af[2], bfr[4];
    #pragma unroll
    for (int i=0;i<2;i++) af[i]  = *(short8*)&Asm[(wr + i*16 + lm)*32 + lk];
    #pragma unroll
    for (int j=0;j<4;j++) bfr[j] = *(short8*)&Bsm[(wc + j*16 + lm)*32 + lk];
    #pragma unroll
    for (int i=0;i<2;i++)
      #pragma unroll
      for (int j=0;j<4;j++)
        acc[i][j] = __builtin_amdgcn_mfma_f32_16x16x32_bf16(af[i], bfr[j], acc[i][j], 0,0,0);
    __syncthreads();
  }

  float asv[4], adv[4];
  #pragma unroll
  for (int j=0;j<4;j++) {
    int col = colBase + wc + j*16 + lm;
    float s = 0.f, d = 0.f;
    if (col < 601)      { s = asr[col];     d = adr[col]; }
    else if (col >= 640 && col - 640 < dn) { s = asn[col-640]; d = adn[col-640]; }
    asv[j] = s; adv[j] = d;
  }
  int cr = lane >> 4;
  int ct2 = cb*2 + (wc >> 6);
  float* esp = (ct2 < 10) ? esed : esed + 2*BN_;
  #pragma unroll
  for (int i=0;i<2;i++) {
    #pragma unroll
    for (int j=0;j<4;j++) {
      int col = colBase + wc + j*16 + lm;
      #pragma unroll
      for (int g=0; g<4; g++) {
        int row = rowBase + wr + i*16 + cr*4 + g;
        C[(size_t)row*HLD_ + col] = f2b(acc[i][j][g]);
      }
    }
    #pragma unroll
    for (int g=0; g<4; g++) {
      float se = 0.f, sd = 0.f;
      #pragma unroll
      for (int j=0;j<4;j++) { se += acc[i][j][g]*asv[j]; sd += acc[i][j][g]*adv[j]; }
      #pragma unroll
      for (int o=1;o<16;o<<=1) { se += __shfl_xor(se,o,64); sd += __shfl_xor(sd,o,64); }
      if (lm == 0) {
        int row = rowBase + wr + i*16 + cr*4 + g;
        atomicAdd(&esp[row], se);
        atomicAdd(&esp[BN_ + row], sd);
      }
    }
  }
}

// ---------------- combined softmax + aggregation (one wave per node) ------
// L<3: writes gbuf (bf16). L==3 (doRsum): skips gbuf entirely; reward cols
// LDS-reduced over the block's 4 nodes and atomicAdd'ed into out[0..OUT_R),
// next-head cols written as f32 to out's ns_new section (same bf16-rounded
// values the old k_final produced).

__global__ __launch_bounds__(256) void k_agg(const ushort* __restrict__ h,
                                             const float* __restrict__ esed,
                                             const int* __restrict__ cnt,
                                             const int* __restrict__ bins,
                                             const float* __restrict__ bias_r,
                                             const float* __restrict__ bias_n,
                                             ushort* __restrict__ g,
                                             float* __restrict__ outp,
                                             int dn, int doRsum) {
  __shared__ float RW[4][608];
  const float* es_r = esed;
  const float* ed_r = esed + BN_;
  const float* es_n = esed + 2*BN_;
  const float* ed_n = esed + 3*BN_;
  int wid = threadIdx.x>>6, lane = threadIdx.x&63;
  int bid = blockIdx.x;
  int xcd = bid & 7, slot = bid >> 3;
  int graph = xcd + ((slot >> 7) << 3);
  int nloc = (slot & 127)*4 + wid;          // node within graph
  int v = graph*512 + nloc;
  int s0 = v * CAP_;
  int deg = cnt[v]; if (deg > CAP_) deg = CAP_;
  float edr = ed_r[v], edn = ed_n[v];

  int nch = (640 + dn + 7) >> 3;   // 96 / 88 / 84 real 8-col chunks
  int ch0 = lane, ch1 = lane + 64;
  bool a1 = ch1 < nch;
  bool c1r = ch1 < 80;
  float acc0[8], acc1[8];
  #pragma unroll
  for (int q=0;q<8;q++){ acc0[q]=0.f; acc1[q]=0.f; }

  if (deg <= 64) {
    bool has = lane < deg;
    int u = 0; float er = -__builtin_inff(), en = -__builtin_inff();
    if (has) {
      u = bins[s0 + lane];
      er = es_r[u] + edr; er = er > 0.f ? er : 0.2f*er;
      en = es_n[u] + edn; en = en > 0.f ? en : 0.2f*en;
    }
    float mr = er, mn = en;
    #pragma unroll
    for (int o=32;o;o>>=1) { mr = fmaxf(mr, __shfl_xor(mr,o,64)); mn = fmaxf(mn, __shfl_xor(mn,o,64)); }
    float pr = has ? __expf(er - mr) : 0.f;
    float pn = has ? __expf(en - mn) : 0.f;
    float dr = pr, dnm = pn;
    #pragma unroll
    for (int o=32;o;o>>=1) { dr += __shfl_xor(dr,o,64); dnm += __shfl_xor(dnm,o,64); }
    pr *= 1.f/(dr + 1e-16f);
    pn *= 1.f/(dnm + 1e-16f);

    for (int t0 = 0; t0 < deg; t0 += 4) {
      int nt = deg - t0; if (nt > 4) nt = 4;
      short8 va[4], vb[4];
      float w0[4], w1[4];
      #pragma unroll
      for (int q=0;q<4;q++) {
        if (q < nt) {
          int uu = __shfl(u, t0+q, 64);
          w0[q] = __shfl(pr, t0+q, 64);
          w1[q] = __shfl(pn, t0+q, 64);
          const ushort* hp = h + (size_t)uu*HLD_;
          va[q] = *(const short8*)&hp[ch0*8];
          vb[q] = a1 ? *(const short8*)&hp[ch1*8] : short8{};
        } else {
          w0[q] = 0.f; w1[q] = 0.f; va[q] = short8{}; vb[q] = short8{};
        }
      }
      #pragma unroll
      for (int q=0;q<4;q++) {
        #pragma unroll
        for (int r=0;r<8;r++) acc0[r] += w0[q] * b2f((ushort)va[q][r]);
        if (a1) {
          float wv = c1r ? w0[q] : w1[q];
          #pragma unroll
          for (int r=0;r<8;r++) acc1[r] += wv * b2f((ushort)vb[q][r]);
        }
      }
    }
  } else {
    int e0 = s0 + deg;
    float mr = -__builtin_inff(), mn = -__builtin_inff();
    for (int j = s0 + lane; j < e0; j += 64) {
      int u = bins[j];
      float er = es_r[u] + edr; er = er>0.f?er:0.2f*er;
      float en = es_n[u] + edn; en = en>0.f?en:0.2f*en;
      mr = fmaxf(mr, er); mn = fmaxf(mn, en);
    }
    #pragma unroll
    for (int o=32;o;o>>=1) { mr=fmaxf(mr,__shfl_xor(mr,o,64)); mn=fmaxf(mn,__shfl_xor(mn,o,64)); }
    float dr=0.f, dnm=0.f;
    for (int j = s0 + lane; j < e0; j += 64) {
      int u = bins[j];
      float er = es_r[u] + edr; er = er>0.f?er:0.2f*er;
      float en = es_n[u] + edn; en = en>0.f?en:0.2f*en;
      dr += __expf(er-mr); dnm += __expf(en-mn);
    }
    #pragma unroll
    for (int o=32;o;o>>=1) { dr+=__shfl_xor(dr,o,64); dnm+=__shfl_xor(dnm,o,64); }
    float ir = 1.f/(dr+1e-16f), in_ = 1.f/(dnm+1e-16f);
    for (int j = s0; j < e0; ++j) {
      int uu = bins[j];
      float er = es_r[uu] + edr; er = er>0.f?er:0.2f*er;
      float en = es_n[uu] + edn; en = en>0.f?en:0.2f*en;
      float wr2 = __expf(er-mr)*ir, wn2 = __expf(en-mn)*in_;
      const ushort* hp = h + (size_t)uu*HLD_;
      short8 hv = *(const short8*)&hp[ch0*8];
      #pragma unroll
      for (int q=0;q<8;q++) acc0[q] += wr2 * b2f((ushort)hv[q]);
      if (a1) {
        short8 hv2 = *(const short8*)&hp[ch1*8];
        float wv = c1r ? wr2 : wn2;
        #pragma unroll
        for (int q=0;q<8;q++) acc1[q] += wv * b2f((ushort)hv2[q]);
      }
    }
  }

  ushort* gv = g + (size_t)v*HLD_;
  {
    int cb = ch0*8;
    short8 ov;
    #pragma unroll
    for (int q=0;q<8;q++) ov[q] = (short)f2b(acc0[q] + bias_r[cb+q]);
    if (!doRsum) {
      *(short8*)&gv[cb] = ov;
    } else {
      #pragma unroll
      for (int q=0;q<8;q++) RW[wid][cb+q] = b2f((ushort)ov[q]);
    }
  }
  if (a1) {
    int cb = ch1*8;
    short8 ov;
    #pragma unroll
    for (int q=0;q<8;q++) {
      int c = cb+q;
      float val;
      if (c < 601)                         val = acc1[q] + bias_r[c];
      else if (c >= 640 && (c-640) < dn)   val = acc1[q] + bias_n[c-640];
      else                                 val = 0.f;
      ov[q] = (short)f2b(val);
    }
    if (!doRsum) {
      *(short8*)&gv[cb] = ov;
    } else {
      if (cb < 608) {
        #pragma unroll
        for (int q=0;q<8;q++) {
          int c = cb+q;
          RW[wid][c] = (c < 601) ? b2f((ushort)ov[q]) : 0.f;
        }
      }
      // next-head f32 write straight to out's ns_new section
      #pragma unroll
      for (int q=0;q<8;q++) {
        int c = cb+q;
        if (c >= 640 && (c-640) < dn) {
          outp[(size_t)OUT_R_ + (size_t)graph*NSROW_ + nloc*D_ + (c-640)] =
              b2f((ushort)ov[q]);
        }
      }
    }
  }
  if (doRsum) {
    if (!a1 && ch1*8 < 608) {     // safety for small nch
      #pragma unroll
      for (int q=0;q<8;q++) RW[wid][ch1*8+q] = 0.f;
    }
    __syncthreads();
    for (int c = threadIdx.x; c < 601; c += 256) {
      float s = RW[0][c] + RW[1][c] + RW[2][c] + RW[3][c];
      atomicAdd(&outp[(size_t)graph*FSS_ + c], s);
    }
  }
}

// ---------------- fused LN: stats + finalize + materialize xbuf -----------
// 1-D grid 192, bid&7 == graph&7 (XCD-affine with agg/gemm).

__global__ __launch_bounds__(256) void k_lnfin(const ushort* __restrict__ g,
                                               const float* __restrict__ scr,
                                               const float* __restrict__ ofr,
                                               const float* __restrict__ scn,
                                               const float* __restrict__ ofn,
                                               ushort* __restrict__ xbuf,
                                               int dn) {
  int bid = blockIdx.x;            // 0..191
  int x = bid & 7, sl = bid >> 3;  // sl in [0,24)
  int b = x + ((sl >= 12) ? 8 : 0);
  int cbk = (sl >= 12) ? (sl - 12) : sl;   // col-block 0..11
  int t = threadIdx.x;
  int c8l = t & 7;               // 8 col-chunks of 8 cols -> 64 cols/block
  int rg  = t >> 3;              // 32 row-groups of 16 rows
  int xb8 = cbk*64 + c8l*8;
  bool okc = xb8 < KXB_;
  int gcol8 = (xb8 < 608) ? xb8 : xb8 + 32;
  float s8[8], q8[8];
  #pragma unroll
  for (int j=0;j<8;j++){ s8[j]=0.f; q8[j]=0.f; }
  if (okc) {
    const ushort* gp = g + (size_t)(b*N_ + rg*16)*HLD_ + gcol8;
    #pragma unroll
    for (int i=0;i<16;i++) {
      short8 v = *(const short8*)&gp[(size_t)i*HLD_];
      #pragma unroll
      for (int j=0;j<8;j++) {
        float xv = b2f((ushort)v[j]);
        s8[j] += xv; q8[j] += xv*xv;
      }
    }
  }
  __shared__ float S[32][64], Q[32][64];
  __shared__ float MU[64], AD[64];
  #pragma unroll
  for (int j=0;j<8;j++){ S[rg][c8l*8+j]=s8[j]; Q[rg][c8l*8+j]=q8[j]; }
  __syncthreads();
  if (t < 64) {
    int xb = cbk*64 + t;
    float mul = 0.f, add = 0.f;
    if (xb < KXB_) {
      float ts=0.f, tq=0.f;
      #pragma unroll
      for (int r=0;r<32;r++){ ts += S[r][t]; tq += Q[r][t]; }
      bool valid; float scale, offs;
      if (xb < 608) { valid = xb < 601;
                      scale = valid ? scr[xb] : 0.f; offs = valid ? ofr[xb] : 0.f; }
      else { int cn = xb - 608; valid = cn < dn;
             scale = valid ? scn[cn] : 0.f; offs = valid ? ofn[cn] : 0.f; }
      if (valid) {
        float mu = ts*(1.f/N_);
        float var = tq*(1.f/N_) - mu*mu;
        float rs = rsqrtf(var+1e-5f);
        mul = rs*scale;
        add = offs - mu*rs*scale;
      }
    }
    MU[t] = mul; AD[t] = add;
  }
  __syncthreads();
  if (okc) {
    float mu8[8], ad8[8];
    #pragma unroll
    for (int j=0;j<8;j++){ mu8[j]=MU[c8l*8+j]; ad8[j]=AD[c8l*8+j]; }
    const ushort* gp = g + (size_t)(b*N_ + rg*16)*HLD_ + gcol8;
    ushort* xp = xbuf + (size_t)(b*N_ + rg*16)*KXB_ + xb8;
    #pragma unroll
    for (int i=0;i<16;i++) {
      short8 v = *(const short8*)&gp[(size_t)i*HLD_];
      short8 ov;
      #pragma unroll
      for (int j=0;j<8;j++) {
        float y = b2f((ushort)v[j]) * mu8[j] + ad8[j];
        y = y > 0.f ? y : 0.f;
        ov[j] = (short)f2b(y);
      }
      *(short8*)&xp[(size_t)i*KXB_] = ov;
    }
  }
}

// ---------------- host driver ----------------

extern "C" void kernel_launch(void* const* d_in, const int* in_sizes, int n_in,
                              void* d_out, int out_size, void* d_ws, size_t ws_size,
                              hipStream_t stream) {
  const float* ns = (const float*)d_in[0];
  const int*   a  = (const int*)d_in[1];

  const float *W[4], *As[4], *Ad[4], *Bb[4], *Sc[3], *Of[3];
  const float *rW[4], *rAs[4], *rAd[4], *rBb[4], *rSc[3], *rOf[3];
  int p = 2;
  for (int i=0;i<4;i++){
    W[i]=(const float*)d_in[p++]; As[i]=(const float*)d_in[p++];
    Ad[i]=(const float*)d_in[p++]; Bb[i]=(const float*)d_in[p++];
    if (i<3){ Sc[i]=(const float*)d_in[p++]; Of[i]=(const float*)d_in[p++]; }
  }
  for (int i=0;i<4;i++){
    rW[i]=(const float*)d_in[p++]; rAs[i]=(const float*)d_in[p++];
    rAd[i]=(const float*)d_in[p++]; rBb[i]=(const float*)d_in[p++];
    if (i<3){ rSc[i]=(const float*)d_in[p++]; rOf[i]=(const float*)d_in[p++]; }
  }

  char* w = (char*)d_ws;
  auto carve = [&](size_t bytes)->void* {
    void* r = (void*)w;
    w += (bytes + 255) & ~(size_t)255;
    return r;
  };
  ushort* hbuf = (ushort*)carve((size_t)BN_*HLD_*2);
  ushort* gbuf = (ushort*)carve((size_t)BN_*HLD_*2);
  ushort* xbuf = (ushort*)carve((size_t)BN_*KXB_*2);   // LN'd activations
  ushort* sabf = (ushort*)carve((size_t)BN_*64*2);
  // zero-region: cnt | esed[4 layers] — one memset covers all
  int* cnt     = (int*)carve((size_t)(BN_ + 16*BN_)*4);
  float* esedL = (float*)(cnt + BN_);                // 4 x [4*BN]
  int* bins    = (int*)carve((size_t)BN_*CAP_*4);    // 4 MB
  ushort* Wt[4];
  Wt[0] = (ushort*)carve((size_t)768*64*2);
  Wt[1] = (ushort*)carve((size_t)768*736*2);
  Wt[2] = (ushort*)carve((size_t)768*672*2);
  Wt[3] = (ushort*)carve((size_t)768*672*2);

  float* out = (float*)d_out;

  hipMemsetAsync(cnt, 0, (size_t)(BN_ + 16*BN_)*4, stream);
  hipMemsetAsync(out, 0, (size_t)OUT_R_*4, stream);   // reward accum target

  SetupP sp;
  sp.ns = ns; sp.a = a; sp.cnt = cnt; sp.bins = bins; sp.sa = sabf; sp.outp = out;
  for (int i=0;i<4;i++){ sp.Wr[i]=rW[i]; sp.Wn[i]=W[i]; sp.T[i]=Wt[i]; }
  // sections: 511 (edges) + 256 (sa) + 256 (ns tail) + 1608 (transpose)
  k_setup<<<2631, 256, 0, stream>>>(sp);

  int Kp[4]   = { 64, 736, 672, 672 };
  int dns[4]  = { 128, 64, 64, 32 };
  int kRe[4]  = { 64, 608, 608, 608 };
  int kNb[4]  = { 0, 608, 608, 608 };

  for (int L=0; L<4; ++L) {
    float* esed = esedL + (size_t)L*4*BN_;
    const ushort* Ain = (L==0) ? sabf : xbuf;
    int Astr        = (L==0) ? 64 : KXB_;
    k_gemm<<<768, 256, 0, stream>>>(Ain, Wt[L], hbuf, esed,
                                    rAs[L], rAd[L], As[L], Ad[L],
                                    Astr, Kp[L], dns[L], kRe[L], kNb[L]);
    k_agg<<<BN_/4, 256, 0, stream>>>(hbuf, esed, cnt, bins,
                                     rBb[L], Bb[L], gbuf, out,
                                     dns[L], (L==3)?1:0);
    if (L < 3) {
      k_lnfin<<<192, 256, 0, stream>>>(gbuf, rSc[L], rOf[L], Sc[L], Of[L],
                                       xbuf, dns[L]);
    }
  }
}